// Round 3
// baseline (313.527 us; speedup 1.0000x reference)
//
#include <hip/hip_runtime.h>
#include <hip/hip_bf16.h>

// Problem constants (fixed by setup_inputs)
#define S_LEN 2048
#define EMB   1024
#define NHEAD 16
#define HDIM  64
#define NBATCH 2
#define M_ROWS (NBATCH * S_LEN)   // 4096

typedef __attribute__((ext_vector_type(8))) __bf16 bf16x8;
typedef __attribute__((ext_vector_type(8))) short short8;
typedef __attribute__((ext_vector_type(4))) short short4_t;
typedef __attribute__((ext_vector_type(4))) float floatx4;

__device__ inline bf16x8 load_frag(const short* p) {
    short8 v = *(const short8*)p;
    return __builtin_bit_cast(bf16x8, v);
}
__device__ inline floatx4 mfma16(bf16x8 a, bf16x8 b, floatx4 c) {
    return __builtin_amdgcn_mfma_f32_16x16x32_bf16(a, b, c, 0, 0, 0);
}
__device__ inline short f2bf_bits(float f) {
    return __builtin_bit_cast(short, __float2bfloat16(f));
}

// ---------------------------------------------------------------------------
// Convert fp32 -> bf16, 8 elems/thread.
// ---------------------------------------------------------------------------
__global__ __launch_bounds__(256) void convert_f32_bf16(
        const float* __restrict__ in, short* __restrict__ out) {
    int idx = (blockIdx.x * 256 + threadIdx.x) * 8;
    float4 a = *(const float4*)&in[idx];
    float4 b = *(const float4*)&in[idx + 4];
    short8 o;
    o[0] = f2bf_bits(a.x); o[1] = f2bf_bits(a.y);
    o[2] = f2bf_bits(a.z); o[3] = f2bf_bits(a.w);
    o[4] = f2bf_bits(b.x); o[5] = f2bf_bits(b.y);
    o[6] = f2bf_bits(b.z); o[7] = f2bf_bits(b.w);
    *(short8*)&out[idx] = o;
}

// ---------------------------------------------------------------------------
// Transpose + convert: out_bf16[c*R + r] = in_f32[r*C + c].  block = (32, 8)
// ---------------------------------------------------------------------------
__global__ __launch_bounds__(256) void transpose_f32_bf16(
        const float* __restrict__ in, short* __restrict__ out, int R, int C) {
    __shared__ float tile[32][33];
    int c = blockIdx.x * 32 + threadIdx.x;
    int r0 = blockIdx.y * 32;
#pragma unroll
    for (int i = 0; i < 4; i++) {
        int r = r0 + threadIdx.y + i * 8;
        tile[threadIdx.y + i * 8][threadIdx.x] = in[(size_t)r * C + c];
    }
    __syncthreads();
    int rr = r0 + threadIdx.x;
    int cc0 = blockIdx.x * 32;
#pragma unroll
    for (int i = 0; i < 4; i++) {
        int cc = cc0 + threadIdx.y + i * 8;
        out[(size_t)cc * R + rr] = f2bf_bits(tile[threadIdx.x][threadIdx.y + i * 8]);
    }
}

// ---------------------------------------------------------------------------
// GEMM core: C[M=4096][N=1024] = A[M][K=1024] * Bt[N][K]^T + bias[N]
// 128x128 tile / block, 4 waves (2x2), each wave 64x64 = 4x4 MFMA tiles.
// MODE 0: plain row-major [M,N], fp32 output (d_out)
// MODE 1: head-split [B,H,S,D], bf16
// MODE 2: head-split transposed [B,H,D,S], bf16, packed 8B stores along S
// ---------------------------------------------------------------------------
template <int MODE>
__device__ void gemm_core(const short* __restrict__ A,
                          const short* __restrict__ Bt,
                          const float* __restrict__ bias,
                          void* __restrict__ Cout) {
    constexpr int Kdim = 1024;
    constexpr int Ndim = 1024;
    constexpr int LDP = 40;  // 32 + 8 pad: 80B row stride (16B aligned)
    __shared__ short lds_a[128 * LDP];
    __shared__ short lds_b[128 * LDP];

    const int t = threadIdx.x;
    const int wave = t >> 6, lane = t & 63;
    const int wm = wave >> 1, wn = wave & 1;
    const int l15 = lane & 15, quad = lane >> 4;
    const int rowA0 = blockIdx.y * 128;
    const int rowB0 = blockIdx.x * 128;

    floatx4 acc[4][4] = {};

    for (int k0 = 0; k0 < Kdim; k0 += 32) {
#pragma unroll
        for (int i = 0; i < 2; i++) {
            int idx = i * 256 + t;
            int row = idx >> 2;
            int col = (idx & 3) * 8;
            short8 va = *(const short8*)&A[(size_t)(rowA0 + row) * Kdim + k0 + col];
            short8 vb = *(const short8*)&Bt[(size_t)(rowB0 + row) * Kdim + k0 + col];
            *(short8*)&lds_a[row * LDP + col] = va;
            *(short8*)&lds_b[row * LDP + col] = vb;
        }
        __syncthreads();
        bf16x8 af[4], bfr[4];
#pragma unroll
        for (int i = 0; i < 4; i++)
            af[i] = load_frag(&lds_a[(wm * 64 + i * 16 + l15) * LDP + quad * 8]);
#pragma unroll
        for (int j = 0; j < 4; j++)
            bfr[j] = load_frag(&lds_b[(wn * 64 + j * 16 + l15) * LDP + quad * 8]);
#pragma unroll
        for (int i = 0; i < 4; i++)
#pragma unroll
            for (int j = 0; j < 4; j++)
                acc[i][j] = mfma16(af[i], bfr[j], acc[i][j]);
        __syncthreads();
    }

    // Epilogue. C/D layout: col = lane&15, row = quad*4 + r.
#pragma unroll
    for (int i = 0; i < 4; i++) {
#pragma unroll
        for (int j = 0; j < 4; j++) {
            int col = rowB0 + wn * 64 + j * 16 + l15;
            float bv = bias[col];
            int row0 = rowA0 + wm * 64 + i * 16 + quad * 4;
            if (MODE == 2) {
                // row = b*2048 + s; col = h*64 + d; write Vt[b][h][d][s..s+3]
                int b = row0 >> 11, s = row0 & 2047;
                int h = col >> 6, d = col & 63;
                short4_t pack;
#pragma unroll
                for (int r = 0; r < 4; r++)
                    pack[r] = f2bf_bits(acc[i][j][r] + bv);
                short* C = (short*)Cout;
                *(short4_t*)&C[((size_t)((b * NHEAD + h) * HDIM + d)) * S_LEN + s] = pack;
            } else if (MODE == 0) {
                float* C = (float*)Cout;
#pragma unroll
                for (int r = 0; r < 4; r++)
                    C[(size_t)(row0 + r) * Ndim + col] = acc[i][j][r] + bv;
            } else {
                short* C = (short*)Cout;
#pragma unroll
                for (int r = 0; r < 4; r++) {
                    int row = row0 + r;
                    int b = row >> 11, s = row & 2047;
                    int h = col >> 6, d = col & 63;
                    C[((size_t)((b * NHEAD + h) * S_LEN + s)) * HDIM + d] =
                        f2bf_bits(acc[i][j][r] + bv);
                }
            }
        }
    }
}

__global__ __launch_bounds__(256) void qkv_gemm(
        const short* __restrict__ x,
        const short* __restrict__ WqT, const short* __restrict__ WkT,
        const short* __restrict__ WvT,
        const float* __restrict__ bq, const float* __restrict__ bk,
        const float* __restrict__ bv,
        short* __restrict__ Q, short* __restrict__ K, short* __restrict__ Vt) {
    if (blockIdx.z == 0)      gemm_core<1>(x, WqT, bq, Q);
    else if (blockIdx.z == 1) gemm_core<1>(x, WkT, bk, K);
    else                      gemm_core<2>(x, WvT, bv, Vt);
}

__global__ __launch_bounds__(256) void out_gemm(
        const short* __restrict__ attn, const short* __restrict__ WoT,
        const float* __restrict__ bo, float* __restrict__ out) {
    gemm_core<0>(attn, WoT, bo, out);
}

// ---------------------------------------------------------------------------
// Flash attention (causal). One block = (b,h) x 64 q rows. 4 waves, each wave
// owns 16 q rows. K tile [64k][64d] and Vt tile [64d][64k] staged in LDS.
// Q: [B,H,S,D], K: [B,H,S,D], Vt: [B,H,D,S], O: [B,S,H,D]  (all bf16)
// ---------------------------------------------------------------------------
__global__ __launch_bounds__(256) void attn_kernel(
        const short* __restrict__ Q, const short* __restrict__ K,
        const short* __restrict__ Vt, short* __restrict__ O) {
    constexpr int LDP = 72;  // 64 + 8 pad; 144B stride (16B aligned)
    __shared__ short lds_k[64 * LDP];
    __shared__ short lds_v[64 * LDP];
    __shared__ short lds_p[4][16 * LDP];

    const int t = threadIdx.x;
    const int wave = t >> 6, lane = t & 63;
    const int l15 = lane & 15, quad = lane >> 4;
    const int bh = blockIdx.y;          // b*NHEAD + h
    const int q0 = blockIdx.x * 64;
    const short* Qh = Q + (size_t)bh * S_LEN * HDIM;
    const short* Kh = K + (size_t)bh * S_LEN * HDIM;
    const short* Vh = Vt + (size_t)bh * HDIM * S_LEN;

    // Q A-fragments for this wave's 16 rows (held in registers for all tiles)
    const int qrowA = q0 + wave * 16 + l15;
    bf16x8 qf0 = load_frag(&Qh[(size_t)qrowA * HDIM + quad * 8]);
    bf16x8 qf1 = load_frag(&Qh[(size_t)qrowA * HDIM + 32 + quad * 8]);

    floatx4 accO[4] = {};
    float m_i[4], l_i[4];
#pragma unroll
    for (int r = 0; r < 4; r++) { m_i[r] = -1e30f; l_i[r] = 0.f; }

    const float scale = 0.03125f;  // 1/sqrt(EMB)
    const int ntiles = blockIdx.x + 1;

    for (int nt = 0; nt < ntiles; nt++) {
        const int kv0 = nt * 64;
        // stage K and Vt tiles (coalesced 16B)
#pragma unroll
        for (int i = 0; i < 2; i++) {
            int idx = i * 256 + t;
            int row = idx >> 3;
            int col = (idx & 7) * 8;
            *(short8*)&lds_k[row * LDP + col] =
                *(const short8*)&Kh[(size_t)(kv0 + row) * HDIM + col];
            *(short8*)&lds_v[row * LDP + col] =
                *(const short8*)&Vh[(size_t)row * S_LEN + kv0 + col];
        }
        __syncthreads();

        // S = Q * K^T  (contraction over d, 2 MFMAs per 16-col tile)
        floatx4 sacc[4] = {};
#pragma unroll
        for (int c = 0; c < 4; c++) {
            bf16x8 kf0 = load_frag(&lds_k[(c * 16 + l15) * LDP + quad * 8]);
            bf16x8 kf1 = load_frag(&lds_k[(c * 16 + l15) * LDP + 32 + quad * 8]);
            sacc[c] = mfma16(qf0, kf0, sacc[c]);
            sacc[c] = mfma16(qf1, kf1, sacc[c]);
        }

        // scale + causal mask + online softmax
        float sv[4][4];
        float rmax[4] = {-1e30f, -1e30f, -1e30f, -1e30f};
#pragma unroll
        for (int c = 0; c < 4; c++) {
#pragma unroll
            for (int r = 0; r < 4; r++) {
                float s = sacc[c][r] * scale;
                int qrow = q0 + wave * 16 + quad * 4 + r;
                int kcol = kv0 + c * 16 + l15;
                if (kcol > qrow) s = -1e30f;
                sv[c][r] = s;
                rmax[r] = fmaxf(rmax[r], s);
            }
        }
#pragma unroll
        for (int off = 8; off >= 1; off >>= 1)
#pragma unroll
            for (int r = 0; r < 4; r++)
                rmax[r] = fmaxf(rmax[r], __shfl_xor(rmax[r], off));

        float alpha[4], rsum[4] = {0.f, 0.f, 0.f, 0.f};
#pragma unroll
        for (int r = 0; r < 4; r++) {
            float mn = fmaxf(m_i[r], rmax[r]);
            alpha[r] = __expf(m_i[r] - mn);
            m_i[r] = mn;
        }
#pragma unroll
        for (int c = 0; c < 4; c++) {
#pragma unroll
            for (int r = 0; r < 4; r++) {
                float p = __expf(sv[c][r] - m_i[r]);
                rsum[r] += p;
                lds_p[wave][(quad * 4 + r) * LDP + c * 16 + l15] = f2bf_bits(p);
            }
        }
#pragma unroll
        for (int off = 8; off >= 1; off >>= 1)
#pragma unroll
            for (int r = 0; r < 4; r++)
                rsum[r] += __shfl_xor(rsum[r], off);
#pragma unroll
        for (int r = 0; r < 4; r++) l_i[r] = l_i[r] * alpha[r] + rsum[r];
#pragma unroll
        for (int dt = 0; dt < 4; dt++)
#pragma unroll
            for (int r = 0; r < 4; r++) accO[dt][r] *= alpha[r];

        // P (C-layout) -> A-layout via LDS (same-wave, in-order), then O += P*V
        bf16x8 pf0 = load_frag(&lds_p[wave][l15 * LDP + quad * 8]);
        bf16x8 pf1 = load_frag(&lds_p[wave][l15 * LDP + 32 + quad * 8]);
#pragma unroll
        for (int dt = 0; dt < 4; dt++) {
            bf16x8 vf0 = load_frag(&lds_v[(dt * 16 + l15) * LDP + quad * 8]);
            bf16x8 vf1 = load_frag(&lds_v[(dt * 16 + l15) * LDP + 32 + quad * 8]);
            accO[dt] = mfma16(pf0, vf0, accO[dt]);
            accO[dt] = mfma16(pf1, vf1, accO[dt]);
        }
        __syncthreads();
    }

    // write O in [B,S,H,D] (== [B,S,E] row-major for the final GEMM)
    const int b = bh >> 4, h = bh & 15;
#pragma unroll
    for (int r = 0; r < 4; r++) {
        float inv = 1.0f / l_i[r];
        int q = q0 + wave * 16 + quad * 4 + r;
#pragma unroll
        for (int dt = 0; dt < 4; dt++) {
            int d = dt * 16 + l15;
            O[((size_t)(b * S_LEN + q) * NHEAD + h) * HDIM + d] =
                f2bf_bits(accO[dt][r] * inv);
        }
    }
}

// ---------------------------------------------------------------------------
extern "C" void kernel_launch(void* const* d_in, const int* in_sizes, int n_in,
                              void* d_out, int out_size, void* d_ws, size_t ws_size,
                              hipStream_t stream) {
    // Inputs fp32; output fp32 (reference computes in float32 end-to-end).
    const float* x  = (const float*)d_in[0];
    const float* Wq = (const float*)d_in[1];
    const float* bq = (const float*)d_in[2];
    const float* Wk = (const float*)d_in[3];
    const float* bk = (const float*)d_in[4];
    const float* Wv = (const float*)d_in[5];
    const float* bv = (const float*)d_in[6];
    const float* Wo = (const float*)d_in[7];
    const float* bo = (const float*)d_in[8];

    // workspace layout (bf16 elements)
    short* ws = (short*)d_ws;
    const size_t WSZ = (size_t)EMB * EMB;          // 1M elems
    const size_t TSZ = (size_t)M_ROWS * EMB;       // 4M elems
    short* xb  = ws;               // [M, E] bf16
    short* WqT = xb + TSZ;
    short* WkT = WqT + WSZ;
    short* WvT = WkT + WSZ;
    short* WoT = WvT + WSZ;
    short* Qb  = WoT + WSZ;        // [B,H,S,D]
    short* Kb  = Qb + TSZ;         // [B,H,S,D]
    short* Vtb = Kb + TSZ;         // [B,H,D,S]
    short* Ab  = Vtb + TSZ;        // attn out [B,S,H,D] = [M, E]
    // total: 5*TSZ + 4*WSZ = 24M bf16 elems = 48 MB

    convert_f32_bf16<<<dim3(M_ROWS * EMB / (256 * 8)), 256, 0, stream>>>(x, xb);

    dim3 tb(32, 8);
    transpose_f32_bf16<<<dim3(32, 32), tb, 0, stream>>>(Wq, WqT, EMB, EMB);
    transpose_f32_bf16<<<dim3(32, 32), tb, 0, stream>>>(Wk, WkT, EMB, EMB);
    transpose_f32_bf16<<<dim3(32, 32), tb, 0, stream>>>(Wv, WvT, EMB, EMB);
    transpose_f32_bf16<<<dim3(32, 32), tb, 0, stream>>>(Wo, WoT, EMB, EMB);

    qkv_gemm<<<dim3(EMB / 128, M_ROWS / 128, 3), 256, 0, stream>>>(
        xb, WqT, WkT, WvT, bq, bk, bv, Qb, Kb, Vtb);

    attn_kernel<<<dim3(S_LEN / 64, NBATCH * NHEAD), 256, 0, stream>>>(Qb, Kb, Vtb, Ab);

    out_gemm<<<dim3(EMB / 128, M_ROWS / 128), 256, 0, stream>>>(
        Ab, WoT, bo, (float*)d_out);
}

// Round 4
// 246.785 us; speedup vs baseline: 1.2704x; 1.2704x over previous
//
#include <hip/hip_runtime.h>
#include <hip/hip_bf16.h>

// Problem constants (fixed by setup_inputs)
#define S_LEN 2048
#define EMB   1024
#define NHEAD 16
#define HDIM  64
#define NBATCH 2
#define M_ROWS (NBATCH * S_LEN)   // 4096

typedef __attribute__((ext_vector_type(8))) __bf16 bf16x8;
typedef __attribute__((ext_vector_type(8))) short short8;
typedef __attribute__((ext_vector_type(4))) short short4_t;
typedef __attribute__((ext_vector_type(4))) float floatx4;

__device__ inline bf16x8 load_frag(const short* p) {
    short8 v = *(const short8*)p;
    return __builtin_bit_cast(bf16x8, v);
}
__device__ inline floatx4 mfma16(bf16x8 a, bf16x8 b, floatx4 c) {
    return __builtin_amdgcn_mfma_f32_16x16x32_bf16(a, b, c, 0, 0, 0);
}
__device__ inline short f2bf_bits(float f) {
    return __builtin_bit_cast(short, __float2bfloat16(f));
}

// ---- async global->LDS (16B/lane). LDS dest is wave-uniform base + lane*16.
#if defined(__has_builtin)
#if __has_builtin(__builtin_amdgcn_global_load_lds)
#define HAVE_ASYNC_LDS 1
#endif
#endif

#ifdef HAVE_ASYNC_LDS
typedef __attribute__((address_space(1))) const void glb_void;
typedef __attribute__((address_space(3))) void lds_void;
__device__ __forceinline__ void load16_to_lds(const void* g, void* l) {
    __builtin_amdgcn_global_load_lds((glb_void*)g, (lds_void*)l, 16, 0, 0);
}
#endif

// ---------------------------------------------------------------------------
// Convert fp32 -> bf16, 8 elems/thread.
// ---------------------------------------------------------------------------
__global__ __launch_bounds__(256) void convert_f32_bf16(
        const float* __restrict__ in, short* __restrict__ out) {
    int idx = (blockIdx.x * 256 + threadIdx.x) * 8;
    float4 a = *(const float4*)&in[idx];
    float4 b = *(const float4*)&in[idx + 4];
    short8 o;
    o[0] = f2bf_bits(a.x); o[1] = f2bf_bits(a.y);
    o[2] = f2bf_bits(a.z); o[3] = f2bf_bits(a.w);
    o[4] = f2bf_bits(b.x); o[5] = f2bf_bits(b.y);
    o[6] = f2bf_bits(b.z); o[7] = f2bf_bits(b.w);
    *(short8*)&out[idx] = o;
}

// ---------------------------------------------------------------------------
// Batched transpose+convert of the 4 weight matrices (all 1024x1024):
// out_bf16[c*1024 + r] = in_f32[r*1024 + c].  block=(32,8), z selects matrix.
// ---------------------------------------------------------------------------
__global__ __launch_bounds__(256) void transpose_w4(
        const float* __restrict__ w0, const float* __restrict__ w1,
        const float* __restrict__ w2, const float* __restrict__ w3,
        short* __restrict__ o0, short* __restrict__ o1,
        short* __restrict__ o2, short* __restrict__ o3) {
    const float* in; short* out;
    switch (blockIdx.z) {
        case 0: in = w0; out = o0; break;
        case 1: in = w1; out = o1; break;
        case 2: in = w2; out = o2; break;
        default: in = w3; out = o3; break;
    }
    __shared__ float tile[32][33];
    int c = blockIdx.x * 32 + threadIdx.x;
    int r0 = blockIdx.y * 32;
#pragma unroll
    for (int i = 0; i < 4; i++) {
        int r = r0 + threadIdx.y + i * 8;
        tile[threadIdx.y + i * 8][threadIdx.x] = in[(size_t)r * EMB + c];
    }
    __syncthreads();
    int rr = r0 + threadIdx.x;
    int cc0 = blockIdx.x * 32;
#pragma unroll
    for (int i = 0; i < 4; i++) {
        int cc = cc0 + threadIdx.y + i * 8;
        out[(size_t)cc * EMB + rr] = f2bf_bits(tile[threadIdx.x][threadIdx.y + i * 8]);
    }
}

// ---------------------------------------------------------------------------
// GEMM core: C[M=4096][N=1024] = A[M][K=1024] * Bt[N][K]^T + bias[N]
// 128x128 tile / block, 4 waves (2x2), each wave 64x64 = 4x4 MFMA tiles.
// Staging via global_load_lds width=16 into UNPADDED [128][32] tiles
// (lane-contiguous layout required by the async op; frag reads are at the
//  8-clk LDS minimum: quad q covers banks {4q..4q+3, 16+4q..}, 8 acc/bank).
// MODE 0: plain row-major [M,N], fp32 output (d_out)
// MODE 1: head-split [B,H,S,D], bf16
// MODE 2: head-split transposed [B,H,D,S], bf16, packed 8B stores along S
// ---------------------------------------------------------------------------
template <int MODE>
__device__ void gemm_core(const short* __restrict__ A,
                          const short* __restrict__ Bt,
                          const float* __restrict__ bias,
                          void* __restrict__ Cout) {
    constexpr int Kdim = 1024;
    constexpr int Ndim = 1024;
    __shared__ short lds_a[128 * 32];
    __shared__ short lds_b[128 * 32];

    const int t = threadIdx.x;
    const int wave = t >> 6, lane = t & 63;
    const int wm = wave >> 1, wn = wave & 1;
    const int l15 = lane & 15, quad = lane >> 4;
    const int rowA0 = blockIdx.y * 128;
    const int rowB0 = blockIdx.x * 128;

    floatx4 acc[4][4] = {};

    for (int k0 = 0; k0 < Kdim; k0 += 32) {
#pragma unroll
        for (int i = 0; i < 2; i++) {
            int idx = i * 256 + t;
            int row = idx >> 2;
            int col = (idx & 3) * 8;
            const short* ga = &A[(size_t)(rowA0 + row) * Kdim + k0 + col];
            const short* gb = &Bt[(size_t)(rowB0 + row) * Kdim + k0 + col];
#ifdef HAVE_ASYNC_LDS
            // wave-uniform LDS base; HW scatters lane*16B -> element idx*8 shorts
            int base = (i * 256 + wave * 64) * 8;
            load16_to_lds(ga, &lds_a[base]);
            load16_to_lds(gb, &lds_b[base]);
#else
            *(short8*)&lds_a[idx * 8] = *(const short8*)ga;
            *(short8*)&lds_b[idx * 8] = *(const short8*)gb;
#endif
        }
        __syncthreads();
        bf16x8 af[4], bfr[4];
#pragma unroll
        for (int i = 0; i < 4; i++)
            af[i] = load_frag(&lds_a[(wm * 64 + i * 16 + l15) * 32 + quad * 8]);
#pragma unroll
        for (int j = 0; j < 4; j++)
            bfr[j] = load_frag(&lds_b[(wn * 64 + j * 16 + l15) * 32 + quad * 8]);
#pragma unroll
        for (int i = 0; i < 4; i++)
#pragma unroll
            for (int j = 0; j < 4; j++)
                acc[i][j] = mfma16(af[i], bfr[j], acc[i][j]);
        __syncthreads();
    }

    // Epilogue. C/D layout: col = lane&15, row = quad*4 + r.
#pragma unroll
    for (int i = 0; i < 4; i++) {
#pragma unroll
        for (int j = 0; j < 4; j++) {
            int col = rowB0 + wn * 64 + j * 16 + l15;
            float bv = bias[col];
            int row0 = rowA0 + wm * 64 + i * 16 + quad * 4;
            if (MODE == 2) {
                // row = b*2048 + s; col = h*64 + d; write Vt[b][h][d][s..s+3]
                int b = row0 >> 11, s = row0 & 2047;
                int h = col >> 6, d = col & 63;
                short4_t pack;
#pragma unroll
                for (int r = 0; r < 4; r++)
                    pack[r] = f2bf_bits(acc[i][j][r] + bv);
                short* C = (short*)Cout;
                *(short4_t*)&C[((size_t)((b * NHEAD + h) * HDIM + d)) * S_LEN + s] = pack;
            } else if (MODE == 0) {
                float* C = (float*)Cout;
#pragma unroll
                for (int r = 0; r < 4; r++)
                    C[(size_t)(row0 + r) * Ndim + col] = acc[i][j][r] + bv;
            } else {
                short* C = (short*)Cout;
#pragma unroll
                for (int r = 0; r < 4; r++) {
                    int row = row0 + r;
                    int b = row >> 11, s = row & 2047;
                    int h = col >> 6, d = col & 63;
                    C[((size_t)((b * NHEAD + h) * S_LEN + s)) * HDIM + d] =
                        f2bf_bits(acc[i][j][r] + bv);
                }
            }
        }
    }
}

__global__ __launch_bounds__(256) void qkv_gemm(
        const short* __restrict__ x,
        const short* __restrict__ WqT, const short* __restrict__ WkT,
        const short* __restrict__ WvT,
        const float* __restrict__ bq, const float* __restrict__ bk,
        const float* __restrict__ bv,
        short* __restrict__ Q, short* __restrict__ K, short* __restrict__ Vt) {
    if (blockIdx.z == 0)      gemm_core<1>(x, WqT, bq, Q);
    else if (blockIdx.z == 1) gemm_core<1>(x, WkT, bk, K);
    else                      gemm_core<2>(x, WvT, bv, Vt);
}

__global__ __launch_bounds__(256) void out_gemm(
        const short* __restrict__ attn, const short* __restrict__ WoT,
        const float* __restrict__ bo, float* __restrict__ out) {
    gemm_core<0>(attn, WoT, bo, out);
}

// ---------------------------------------------------------------------------
// Flash attention (causal). One block = (b,h) x 64 q rows. 4 waves, each wave
// owns 16 q rows. K tile [64k][64d] and Vt tile [64d][64k] staged in LDS.
// Grid: (bh fastest, qtile-slot) with qtile = 31 - blockIdx.y so the heavy
// blocks dispatch first and each CU gets a mixed qtile set (load balance).
// Q: [B,H,S,D], K: [B,H,S,D], Vt: [B,H,D,S], O: [B,S,H,D]  (all bf16)
// ---------------------------------------------------------------------------
__global__ __launch_bounds__(256) void attn_kernel(
        const short* __restrict__ Q, const short* __restrict__ K,
        const short* __restrict__ Vt, short* __restrict__ O) {
    constexpr int LDP = 72;  // 64 + 8 pad; 144B stride (16B aligned)
    __shared__ short lds_k[64 * LDP];
    __shared__ short lds_v[64 * LDP];
    __shared__ short lds_p[4][16 * LDP];

    const int t = threadIdx.x;
    const int wave = t >> 6, lane = t & 63;
    const int l15 = lane & 15, quad = lane >> 4;
    const int bh = blockIdx.x;                         // b*NHEAD + h
    const int qt = (S_LEN / 64 - 1) - blockIdx.y;      // heavy-first
    const int q0 = qt * 64;
    const short* Qh = Q + (size_t)bh * S_LEN * HDIM;
    const short* Kh = K + (size_t)bh * S_LEN * HDIM;
    const short* Vh = Vt + (size_t)bh * HDIM * S_LEN;

    // Q A-fragments for this wave's 16 rows (held in registers for all tiles)
    const int qrowA = q0 + wave * 16 + l15;
    bf16x8 qf0 = load_frag(&Qh[(size_t)qrowA * HDIM + quad * 8]);
    bf16x8 qf1 = load_frag(&Qh[(size_t)qrowA * HDIM + 32 + quad * 8]);

    floatx4 accO[4] = {};
    float m_i[4], l_i[4];
#pragma unroll
    for (int r = 0; r < 4; r++) { m_i[r] = -1e30f; l_i[r] = 0.f; }

    const float scale = 0.03125f;  // 1/sqrt(EMB)
    const int ntiles = qt + 1;

    for (int nt = 0; nt < ntiles; nt++) {
        const int kv0 = nt * 64;
        // stage K and Vt tiles (coalesced 16B)
#pragma unroll
        for (int i = 0; i < 2; i++) {
            int idx = i * 256 + t;
            int row = idx >> 3;
            int col = (idx & 7) * 8;
            *(short8*)&lds_k[row * LDP + col] =
                *(const short8*)&Kh[(size_t)(kv0 + row) * HDIM + col];
            *(short8*)&lds_v[row * LDP + col] =
                *(const short8*)&Vh[(size_t)row * S_LEN + kv0 + col];
        }
        __syncthreads();

        // S = Q * K^T  (contraction over d, 2 MFMAs per 16-col tile)
        floatx4 sacc[4] = {};
#pragma unroll
        for (int c = 0; c < 4; c++) {
            bf16x8 kf0 = load_frag(&lds_k[(c * 16 + l15) * LDP + quad * 8]);
            bf16x8 kf1 = load_frag(&lds_k[(c * 16 + l15) * LDP + 32 + quad * 8]);
            sacc[c] = mfma16(qf0, kf0, sacc[c]);
            sacc[c] = mfma16(qf1, kf1, sacc[c]);
        }

        // scale + causal mask + online softmax
        float sv[4][4];
        float rmax[4] = {-1e30f, -1e30f, -1e30f, -1e30f};
#pragma unroll
        for (int c = 0; c < 4; c++) {
#pragma unroll
            for (int r = 0; r < 4; r++) {
                float s = sacc[c][r] * scale;
                int qrow = q0 + wave * 16 + quad * 4 + r;
                int kcol = kv0 + c * 16 + l15;
                if (kcol > qrow) s = -1e30f;
                sv[c][r] = s;
                rmax[r] = fmaxf(rmax[r], s);
            }
        }
#pragma unroll
        for (int off = 8; off >= 1; off >>= 1)
#pragma unroll
            for (int r = 0; r < 4; r++)
                rmax[r] = fmaxf(rmax[r], __shfl_xor(rmax[r], off));

        float alpha[4], rsum[4] = {0.f, 0.f, 0.f, 0.f};
#pragma unroll
        for (int r = 0; r < 4; r++) {
            float mn = fmaxf(m_i[r], rmax[r]);
            alpha[r] = __expf(m_i[r] - mn);
            m_i[r] = mn;
        }
#pragma unroll
        for (int c = 0; c < 4; c++) {
#pragma unroll
            for (int r = 0; r < 4; r++) {
                float p = __expf(sv[c][r] - m_i[r]);
                rsum[r] += p;
                lds_p[wave][(quad * 4 + r) * LDP + c * 16 + l15] = f2bf_bits(p);
            }
        }
#pragma unroll
        for (int off = 8; off >= 1; off >>= 1)
#pragma unroll
            for (int r = 0; r < 4; r++)
                rsum[r] += __shfl_xor(rsum[r], off);
#pragma unroll
        for (int r = 0; r < 4; r++) l_i[r] = l_i[r] * alpha[r] + rsum[r];
#pragma unroll
        for (int dt = 0; dt < 4; dt++)
#pragma unroll
            for (int r = 0; r < 4; r++) accO[dt][r] *= alpha[r];

        // P (C-layout) -> A-layout via LDS (same-wave, in-order), then O += P*V
        bf16x8 pf0 = load_frag(&lds_p[wave][l15 * LDP + quad * 8]);
        bf16x8 pf1 = load_frag(&lds_p[wave][l15 * LDP + 32 + quad * 8]);
#pragma unroll
        for (int dt = 0; dt < 4; dt++) {
            bf16x8 vf0 = load_frag(&lds_v[(dt * 16 + l15) * LDP + quad * 8]);
            bf16x8 vf1 = load_frag(&lds_v[(dt * 16 + l15) * LDP + 32 + quad * 8]);
            accO[dt] = mfma16(pf0, vf0, accO[dt]);
            accO[dt] = mfma16(pf1, vf1, accO[dt]);
        }
        __syncthreads();
    }

    // write O in [B,S,H,D] (== [B,S,E] row-major for the final GEMM)
    const int b = bh >> 4, h = bh & 15;
#pragma unroll
    for (int r = 0; r < 4; r++) {
        float inv = 1.0f / l_i[r];
        int q = q0 + wave * 16 + quad * 4 + r;
#pragma unroll
        for (int dt = 0; dt < 4; dt++) {
            int d = dt * 16 + l15;
            O[((size_t)(b * S_LEN + q) * NHEAD + h) * HDIM + d] =
                f2bf_bits(accO[dt][r] * inv);
        }
    }
}

// ---------------------------------------------------------------------------
extern "C" void kernel_launch(void* const* d_in, const int* in_sizes, int n_in,
                              void* d_out, int out_size, void* d_ws, size_t ws_size,
                              hipStream_t stream) {
    // Inputs fp32; output fp32 (reference computes in float32 end-to-end).
    const float* x  = (const float*)d_in[0];
    const float* Wq = (const float*)d_in[1];
    const float* bq = (const float*)d_in[2];
    const float* Wk = (const float*)d_in[3];
    const float* bk = (const float*)d_in[4];
    const float* Wv = (const float*)d_in[5];
    const float* bv = (const float*)d_in[6];
    const float* Wo = (const float*)d_in[7];
    const float* bo = (const float*)d_in[8];

    // workspace layout (bf16 elements)
    short* ws = (short*)d_ws;
    const size_t WSZ = (size_t)EMB * EMB;          // 1M elems
    const size_t TSZ = (size_t)M_ROWS * EMB;       // 4M elems
    short* xb  = ws;               // [M, E] bf16
    short* WqT = xb + TSZ;
    short* WkT = WqT + WSZ;
    short* WvT = WkT + WSZ;
    short* WoT = WvT + WSZ;
    short* Qb  = WoT + WSZ;        // [B,H,S,D]
    short* Kb  = Qb + TSZ;         // [B,H,S,D]
    short* Vtb = Kb + TSZ;         // [B,H,D,S]
    short* Ab  = Vtb + TSZ;        // attn out [B,S,H,D] = [M, E]
    // total: 5*TSZ + 4*WSZ = 24M bf16 elems = 48 MB

    convert_f32_bf16<<<dim3(M_ROWS * EMB / (256 * 8)), 256, 0, stream>>>(x, xb);

    transpose_w4<<<dim3(32, 32, 4), dim3(32, 8), 0, stream>>>(
        Wq, Wk, Wv, Wo, WqT, WkT, WvT, WoT);

    qkv_gemm<<<dim3(EMB / 128, M_ROWS / 128, 3), 256, 0, stream>>>(
        xb, WqT, WkT, WvT, bq, bk, bv, Qb, Kb, Vtb);

    attn_kernel<<<dim3(NBATCH * NHEAD, S_LEN / 64), 256, 0, stream>>>(Qb, Kb, Vtb, Ab);

    out_gemm<<<dim3(EMB / 128, M_ROWS / 128), 256, 0, stream>>>(
        Ab, WoT, bo, (float*)d_out);
}